// Round 3
// baseline (80.016 us; speedup 1.0000x reference)
//
#include <hip/hip_runtime.h>

constexpr int Bn = 1024;
constexpr int Nn = 128;   // pred points per batch
constexpr int Mn = 128;   // gt points per batch

// interp[m,t] = a + (t/10)*e, a=gt[m-1], e=gt[m]-gt[m-1]. dist quadratic in t ->
// discrete vertex only. Argmin via packed uint key: (bits(d) & ~0x7F) | idx
// (d>=0 so float bits are order-monotonic; ties -> smaller idx = np semantics).

__global__ __launch_bounds__(256) void dm_main(
    const float2* __restrict__ ini,    // [B,N]
    const float2* __restrict__ pred,   // [B,N]
    const float2* __restrict__ gt,     // [B,M]
    const float*  __restrict__ kpm,    // [B,M]
    float4* __restrict__ part)         // [2B]
{
    __shared__ float4 s_segA[Mn];   // a.x, a.y, e.x, e.y
    __shared__ float2 s_segB[Mn];   // ee, -10*rcp(ee)
    __shared__ float2 s_ini[Nn];
    __shared__ float2 s_pred[Nn];
    __shared__ float2 s_gt[Mn];
    __shared__ float  s_red[3][4];

    const int b   = blockIdx.x >> 1;   // batch
    const int h   = blockIdx.x & 1;    // which 64-point half this block owns
    const int tid = threadIdx.x;

    if (tid < Mn) {
        const float2 cur = gt[b*Mn + tid];
        const float2 prv = gt[b*Mn + ((tid + Mn - 1) & (Mn - 1))];
        const float ex = cur.x - prv.x, ey = cur.y - prv.y;
        const float ee = fmaxf(fmaf(ex, ex, ey*ey), 1e-30f);
        s_segA[tid] = make_float4(prv.x, prv.y, ex, ey);
        s_segB[tid] = make_float2(ee, -10.0f * __builtin_amdgcn_rcpf(ee));
        s_gt[tid]   = cur;
        s_ini[tid]  = ini[b*Nn + tid];
        s_pred[tid] = pred[b*Nn + tid];
    }
    __syncthreads();

    const int p    = tid >> 2;      // local point 0..63
    const int q    = tid & 3;       // quarter of the scan
    const int n    = h*64 + p;      // global point index 0..127
    const int base = q*32;

    // ---- phase A: nearest interpolated gt point for pred point n ----
    const float2 P = s_ini[n];
    unsigned bestA = 0xFFFFFFFFu;
    #pragma unroll 8
    for (int i = 0; i < 32; ++i) {
        const int m = base + i;
        const float4 A  = s_segA[m];
        const float2 Bv = s_segB[m];
        const float fx = A.x - P.x, fy = A.y - P.y;
        const float fe = fmaf(fx, A.z, fy*A.w);
        const float ff = fmaf(fx, fx, fy*fy);
        const float sp = 0.1f * __builtin_amdgcn_fmed3f(rintf(fe*Bv.y), 0.f, 9.f);
        const float d  = fmaxf(fmaf(sp, fmaf(sp, Bv.x, fe + fe), ff), 0.f);
        bestA = min(bestA, (__float_as_uint(d) & 0xFFFFFF80u) | (unsigned)m);
    }
    bestA = min(bestA, (unsigned)__shfl_xor((int)bestA, 1));
    bestA = min(bestA, (unsigned)__shfl_xor((int)bestA, 2));

    float sum_p2g = 0.f;
    if (q == 0) {
        const int bm = bestA & 127;
        const float4 A  = s_segA[bm];
        const float2 Bv = s_segB[bm];
        const float fx = A.x - P.x, fy = A.y - P.y;
        const float fe = fmaf(fx, A.z, fy*A.w);
        const float sp = 0.1f * __builtin_amdgcn_fmed3f(rintf(fe*Bv.y), 0.f, 9.f);
        const float ngx = fmaf(sp, A.z, A.x);
        const float ngy = fmaf(sp, A.w, A.y);
        const float2 pr = s_pred[n];
        sum_p2g = fabsf(pr.x - ngx) + fabsf(pr.y - ngy);
    }

    // ---- phase B: nearest pred anchor for gt point m=n ----
    const float2 g = s_gt[n];
    unsigned bestB = 0xFFFFFFFFu;
    #pragma unroll 8
    for (int i = 0; i < 32; ++i) {
        const int j = base + i;
        const float2 Qp = s_ini[j];
        const float dx = Qp.x - g.x, dy = Qp.y - g.y;
        const float d  = fmaf(dx, dx, dy*dy);
        bestB = min(bestB, (__float_as_uint(d) & 0xFFFFFF80u) | (unsigned)j);
    }
    bestB = min(bestB, (unsigned)__shfl_xor((int)bestB, 1));
    bestB = min(bestB, (unsigned)__shfl_xor((int)bestB, 2));

    float sum_g2p = 0.f, sum_m = 0.f;
    if (q == 0) {
        const int   ni_ = bestB & 127;
        const float w   = kpm[b*Mn + n];
        const float2 np_ = s_pred[ni_];
        sum_g2p = w * (fabsf(np_.x - g.x) + fabsf(np_.y - g.y));
        sum_m   = 2.0f * w;
    }

    // ---- block reduction over 256 threads ----
    #pragma unroll
    for (int off = 32; off > 0; off >>= 1) {
        sum_p2g += __shfl_down(sum_p2g, off);
        sum_g2p += __shfl_down(sum_g2p, off);
        sum_m   += __shfl_down(sum_m,   off);
    }
    const int wv = tid >> 6;
    if ((tid & 63) == 0) { s_red[0][wv] = sum_p2g; s_red[1][wv] = sum_g2p; s_red[2][wv] = sum_m; }
    __syncthreads();
    if (tid == 0) {
        part[blockIdx.x] = make_float4(
            s_red[0][0] + s_red[0][1] + s_red[0][2] + s_red[0][3],
            s_red[1][0] + s_red[1][1] + s_red[1][2] + s_red[1][3],
            s_red[2][0] + s_red[2][1] + s_red[2][2] + s_red[2][3], 0.f);
    }
}

__global__ __launch_bounds__(1024) void dm_final(const float4* __restrict__ part,
                                                 float* __restrict__ out)
{
    __shared__ float s_red[3][16];
    const int tid = threadIdx.x;
    const float4 v0 = part[tid];
    const float4 v1 = part[tid + 1024];
    float a = v0.x + v1.x, c = v0.y + v1.y, m = v0.z + v1.z;
    #pragma unroll
    for (int off = 32; off > 0; off >>= 1) {
        a += __shfl_down(a, off); c += __shfl_down(c, off); m += __shfl_down(m, off);
    }
    const int wv = tid >> 6;
    if ((tid & 63) == 0) { s_red[0][wv] = a; s_red[1][wv] = c; s_red[2][wv] = m; }
    __syncthreads();
    if (tid == 0) {
        float A = 0.f, C = 0.f, M = 0.f;
        #pragma unroll
        for (int i = 0; i < 16; ++i) { A += s_red[0][i]; C += s_red[1][i]; M += s_red[2][i]; }
        out[0] = (C / (M + 1.0f) + A * (1.0f / 262144.0f)) * 0.5f;
    }
}

extern "C" void kernel_launch(void* const* d_in, const int* in_sizes, int n_in,
                              void* d_out, int out_size, void* d_ws, size_t ws_size,
                              hipStream_t stream)
{
    const float2* ini  = (const float2*)d_in[0];
    const float2* pred = (const float2*)d_in[1];
    const float2* gt   = (const float2*)d_in[2];
    const float*  kpm  = (const float*)d_in[3];
    float*  out  = (float*)d_out;
    float4* part = (float4*)d_ws;   // 2048 * 16 B, fully rewritten every call

    dm_main<<<2*Bn, 256, 0, stream>>>(ini, pred, gt, kpm, part);
    dm_final<<<1, 1024, 0, stream>>>(part, out);
}

// Round 4
// 77.537 us; speedup vs baseline: 1.0320x; 1.0320x over previous
//
#include <hip/hip_runtime.h>

constexpr int Bn = 1024;
constexpr int Mn = 128;   // gt points (= pred points) per batch

// interp[m,t] = a + (t/10)*e, a=gt[m-1], e=gt[m]-gt[m-1]; dist quadratic in t ->
// evaluate discrete vertex only. Segment/anchor data is BLOCK-UNIFORM, so the
// hot loop reads it via uniform (scalar s_load) accesses: no LDS, no DS pipe.
// Argmin key: (bits(d) & ~0x7F) | idx  (d>=0 -> monotone bits; ties -> lower idx).

__global__ __launch_bounds__(256) void dm_pre(
    const float2* __restrict__ ini,   // [B,M]
    const float2* __restrict__ gt,    // [B,M]
    float4* __restrict__ seg)         // [B*M*2]: {a.x,a.y,e.x,e.y},{ee,nr,ini.x,ini.y}
{
    const int idx = blockIdx.x * 256 + threadIdx.x;   // = b*128 + m
    const int b = idx >> 7, m = idx & 127;
    const float2 cur = gt[idx];
    const float2 prv = gt[(b << 7) | ((m + 127) & 127)];
    const float2 ii  = ini[idx];
    const float ex = cur.x - prv.x, ey = cur.y - prv.y;
    const float ee = fmaxf(fmaf(ex, ex, ey * ey), 1e-30f);
    const float nr = -10.0f * __builtin_amdgcn_rcpf(ee);
    seg[2*idx]     = make_float4(prv.x, prv.y, ex, ey);
    seg[2*idx + 1] = make_float4(ee, nr, ii.x, ii.y);
}

__global__ __launch_bounds__(128) void dm_main(
    const float2* __restrict__ ini,    // [B,M]
    const float2* __restrict__ pred,   // [B,M]
    const float2* __restrict__ gt,     // [B,M]
    const float*  __restrict__ kpm,    // [B,M]
    const float4* __restrict__ seg,    // [B*M*2] packed constants (uniform-read)
    float4* __restrict__ part)         // [B]
{
    const int b    = blockIdx.x;
    const int tid  = threadIdx.x;
    const int base = b * (2 * Mn);

    const float2 P = ini[b*Mn + tid];   // per-lane point for phase A
    const float2 g = gt [b*Mn + tid];   // per-lane point for phase B

    unsigned bestA = 0xFFFFFFFFu, bestB = 0xFFFFFFFFu;
    #pragma unroll 8
    for (int m = 0; m < Mn; ++m) {
        const float4 A1 = seg[base + 2*m];       // uniform -> s_load (SMEM pipe)
        const float4 A2 = seg[base + 2*m + 1];
        // phase A: nearest interpolated gt point for pred point tid
        const float fx = A1.x - P.x, fy = A1.y - P.y;
        const float fe = fmaf(fx, A1.z, fy*A1.w);
        const float ff = fmaf(fx, fx, fy*fy);
        const float sp = 0.1f * __builtin_amdgcn_fmed3f(rintf(fe*A2.y), 0.f, 9.f);
        const float d  = fmaxf(fmaf(sp, fmaf(sp, A2.x, fe + fe), ff), 0.f);
        bestA = min(bestA, (__float_as_uint(d) & 0xFFFFFF80u) | (unsigned)m);
        // phase B: nearest pred anchor for gt point tid
        const float dx = A2.z - g.x, dy = A2.w - g.y;
        const float d2 = fmaf(dx, dx, dy*dy);
        bestB = min(bestB, (__float_as_uint(d2) & 0xFFFFFF80u) | (unsigned)m);
    }

    // ---- reconstruct nearest interp point (one divergent, L1-hot load) ----
    const int bm = bestA & 127;
    const float4 R1 = seg[base + 2*bm];
    const float4 R2 = seg[base + 2*bm + 1];
    const float fx = R1.x - P.x, fy = R1.y - P.y;
    const float fe = fmaf(fx, R1.z, fy*R1.w);
    const float sp = 0.1f * __builtin_amdgcn_fmed3f(rintf(fe*R2.y), 0.f, 9.f);
    const float ngx = fmaf(sp, R1.z, R1.x);
    const float ngy = fmaf(sp, R1.w, R1.y);
    const float2 pr = pred[b*Mn + tid];
    float sum_p2g = fabsf(pr.x - ngx) + fabsf(pr.y - ngy);

    const int   ni_ = bestB & 127;
    const float2 np_ = pred[b*Mn + ni_];
    const float  w   = kpm[b*Mn + tid];
    float sum_g2p = w * (fabsf(np_.x - g.x) + fabsf(np_.y - g.y));
    float sum_m   = 2.0f * w;

    // ---- block reduction: 3 scalars over 2 waves ----
    __shared__ float s_red[3][2];
    #pragma unroll
    for (int off = 32; off > 0; off >>= 1) {
        sum_p2g += __shfl_down(sum_p2g, off);
        sum_g2p += __shfl_down(sum_g2p, off);
        sum_m   += __shfl_down(sum_m,   off);
    }
    const int wv = tid >> 6;
    if ((tid & 63) == 0) { s_red[0][wv] = sum_p2g; s_red[1][wv] = sum_g2p; s_red[2][wv] = sum_m; }
    __syncthreads();
    if (tid == 0) {
        part[b] = make_float4(s_red[0][0] + s_red[0][1],
                              s_red[1][0] + s_red[1][1],
                              s_red[2][0] + s_red[2][1], 0.f);
    }
}

__global__ __launch_bounds__(1024) void dm_final(const float4* __restrict__ part,
                                                 float* __restrict__ out)
{
    __shared__ float s_red[3][16];
    const int tid = threadIdx.x;
    const float4 v = part[tid];
    float a = v.x, c = v.y, m = v.z;
    #pragma unroll
    for (int off = 32; off > 0; off >>= 1) {
        a += __shfl_down(a, off); c += __shfl_down(c, off); m += __shfl_down(m, off);
    }
    const int wv = tid >> 6;
    if ((tid & 63) == 0) { s_red[0][wv] = a; s_red[1][wv] = c; s_red[2][wv] = m; }
    __syncthreads();
    if (tid == 0) {
        float A = 0.f, C = 0.f, M = 0.f;
        #pragma unroll
        for (int i = 0; i < 16; ++i) { A += s_red[0][i]; C += s_red[1][i]; M += s_red[2][i]; }
        out[0] = (C / (M + 1.0f) + A * (1.0f / 262144.0f)) * 0.5f;
    }
}

extern "C" void kernel_launch(void* const* d_in, const int* in_sizes, int n_in,
                              void* d_out, int out_size, void* d_ws, size_t ws_size,
                              hipStream_t stream)
{
    const float2* ini  = (const float2*)d_in[0];
    const float2* pred = (const float2*)d_in[1];
    const float2* gt   = (const float2*)d_in[2];
    const float*  kpm  = (const float*)d_in[3];
    float* out = (float*)d_out;

    float4* seg  = (float4*)d_ws;          // 4 MiB: packed segment/anchor constants
    float4* part = seg + Bn * Mn * 2;      // 16 KiB: per-batch partials

    dm_pre <<<Bn * Mn / 256, 256, 0, stream>>>(ini, gt, seg);
    dm_main<<<Bn, 128, 0, stream>>>(ini, pred, gt, kpm, seg, part);
    dm_final<<<1, 1024, 0, stream>>>(part, out);
}

// Round 5
// 74.925 us; speedup vs baseline: 1.0679x; 1.0349x over previous
//
#include <hip/hip_runtime.h>

constexpr int Bn = 1024;
constexpr int Mn = 128;   // gt points (= pred points) per batch

// interp[m,t] = a + (t/10)*e, a=gt[m-1], e=gt[m]-gt[m-1]; dist quadratic in t ->
// evaluate the discrete vertex only. Segment/anchor constants are wave-uniform in
// the hot loop -> scalar s_load (SMEM pipe), zero LDS/DS traffic in the scan.
// Argmin key: (bits(d) & ~0x7F) | idx  (d>=0 -> monotone bits; ties -> lower idx).

__global__ __launch_bounds__(256) void dm_pre(
    const float2* __restrict__ ini,   // [B,M]
    const float2* __restrict__ gt,    // [B,M]
    float4* __restrict__ seg)         // [B*M*2]: {a.x,a.y,e.x,e.y},{ee,nr,ini.x,ini.y}
{
    const int idx = blockIdx.x * 256 + threadIdx.x;   // = b*128 + m
    const int b = idx >> 7, m = idx & 127;
    const float2 cur = gt[idx];
    const float2 prv = gt[(b << 7) | ((m + 127) & 127)];
    const float2 ii  = ini[idx];
    const float ex = cur.x - prv.x, ey = cur.y - prv.y;
    const float ee = fmaxf(fmaf(ex, ex, ey * ey), 1e-30f);
    const float nr = -10.0f * __builtin_amdgcn_rcpf(ee);
    seg[2*idx]     = make_float4(prv.x, prv.y, ex, ey);
    seg[2*idx + 1] = make_float4(ee, nr, ii.x, ii.y);
}

__global__ __launch_bounds__(512) void dm_main(
    const float2* __restrict__ ini,    // [B,M]
    const float2* __restrict__ pred,   // [B,M]
    const float2* __restrict__ gt,     // [B,M]
    const float*  __restrict__ kpm,    // [B,M]
    const float4* __restrict__ seg,    // [B*M*2] packed constants (uniform s_load)
    float4* __restrict__ part)         // [B]
{
    __shared__ unsigned sA[4][Mn];
    __shared__ unsigned sB[4][Mn];
    __shared__ float    s_red[3][8];

    const int b   = blockIdx.x;
    const int tid = threadIdx.x;
    const int p   = tid & 127;                                   // point 0..127
    const int q   = __builtin_amdgcn_readfirstlane(tid >> 7);    // quarter, FORCED uniform
    const int base = b * (2 * Mn);

    const float2 P = ini[b*Mn + p];   // per-lane point for phase A
    const float2 g = gt [b*Mn + p];   // per-lane point for phase B

    unsigned bestA = 0xFFFFFFFFu, bestB = 0xFFFFFFFFu;
    #pragma unroll 8
    for (int i = 0; i < 32; ++i) {
        const int m = q*32 + i;                   // wave-uniform -> s_load
        const float4 A1 = seg[base + 2*m];
        const float4 A2 = seg[base + 2*m + 1];
        // phase A: nearest interpolated gt point for pred point p
        const float fx = A1.x - P.x, fy = A1.y - P.y;
        const float fe = fmaf(fx, A1.z, fy*A1.w);
        const float ff = fmaf(fx, fx, fy*fy);
        const float sp = 0.1f * __builtin_amdgcn_fmed3f(rintf(fe*A2.y), 0.f, 9.f);
        const float d  = fmaxf(fmaf(sp, fmaf(sp, A2.x, fe + fe), ff), 0.f);
        bestA = min(bestA, (__float_as_uint(d) & 0xFFFFFF80u) | (unsigned)m);
        // phase B: nearest pred anchor for gt point p
        const float dx = A2.z - g.x, dy = A2.w - g.y;
        const float d2 = fmaf(dx, dx, dy*dy);
        bestB = min(bestB, (__float_as_uint(d2) & 0xFFFFFF80u) | (unsigned)m);
    }
    sA[q][p] = bestA;
    sB[q][p] = bestB;
    __syncthreads();

    float sum_p2g = 0.f, sum_g2p = 0.f, sum_m = 0.f;
    if (tid < Mn) {
        bestA = min(min(sA[0][p], sA[1][p]), min(sA[2][p], sA[3][p]));
        bestB = min(min(sB[0][p], sB[1][p]), min(sB[2][p], sB[3][p]));

        // reconstruct nearest interp point (divergent, L1-hot)
        const int bm = bestA & 127;
        const float4 R1 = seg[base + 2*bm];
        const float4 R2 = seg[base + 2*bm + 1];
        const float fx = R1.x - P.x, fy = R1.y - P.y;
        const float fe = fmaf(fx, R1.z, fy*R1.w);
        const float sp = 0.1f * __builtin_amdgcn_fmed3f(rintf(fe*R2.y), 0.f, 9.f);
        const float ngx = fmaf(sp, R1.z, R1.x);
        const float ngy = fmaf(sp, R1.w, R1.y);
        const float2 pr = pred[b*Mn + p];
        sum_p2g = fabsf(pr.x - ngx) + fabsf(pr.y - ngy);

        const int   ni_ = bestB & 127;
        const float2 np_ = pred[b*Mn + ni_];
        const float  w   = kpm[b*Mn + p];
        sum_g2p = w * (fabsf(np_.x - g.x) + fabsf(np_.y - g.y));
        sum_m   = 2.0f * w;
    }

    // block reduction: 3 scalars over 8 waves (only wave 0-1 carry nonzero)
    #pragma unroll
    for (int off = 32; off > 0; off >>= 1) {
        sum_p2g += __shfl_down(sum_p2g, off);
        sum_g2p += __shfl_down(sum_g2p, off);
        sum_m   += __shfl_down(sum_m,   off);
    }
    const int wv = tid >> 6;
    if ((tid & 63) == 0) { s_red[0][wv] = sum_p2g; s_red[1][wv] = sum_g2p; s_red[2][wv] = sum_m; }
    __syncthreads();
    if (tid == 0) {
        part[b] = make_float4(s_red[0][0] + s_red[0][1],
                              s_red[1][0] + s_red[1][1],
                              s_red[2][0] + s_red[2][1], 0.f);
    }
}

__global__ __launch_bounds__(1024) void dm_final(const float4* __restrict__ part,
                                                 float* __restrict__ out)
{
    __shared__ float s_red[3][16];
    const int tid = threadIdx.x;
    const float4 v = part[tid];
    float a = v.x, c = v.y, m = v.z;
    #pragma unroll
    for (int off = 32; off > 0; off >>= 1) {
        a += __shfl_down(a, off); c += __shfl_down(c, off); m += __shfl_down(m, off);
    }
    const int wv = tid >> 6;
    if ((tid & 63) == 0) { s_red[0][wv] = a; s_red[1][wv] = c; s_red[2][wv] = m; }
    __syncthreads();
    if (tid == 0) {
        float A = 0.f, C = 0.f, M = 0.f;
        #pragma unroll
        for (int i = 0; i < 16; ++i) { A += s_red[0][i]; C += s_red[1][i]; M += s_red[2][i]; }
        out[0] = (C / (M + 1.0f) + A * (1.0f / 262144.0f)) * 0.5f;
    }
}

extern "C" void kernel_launch(void* const* d_in, const int* in_sizes, int n_in,
                              void* d_out, int out_size, void* d_ws, size_t ws_size,
                              hipStream_t stream)
{
    const float2* ini  = (const float2*)d_in[0];
    const float2* pred = (const float2*)d_in[1];
    const float2* gt   = (const float2*)d_in[2];
    const float*  kpm  = (const float*)d_in[3];
    float* out = (float*)d_out;

    float4* seg  = (float4*)d_ws;          // 4 MiB packed constants
    float4* part = seg + Bn * Mn * 2;      // 16 KiB per-batch partials

    dm_pre <<<Bn * Mn / 256, 256, 0, stream>>>(ini, gt, seg);
    dm_main<<<Bn, 512, 0, stream>>>(ini, pred, gt, kpm, seg, part);
    dm_final<<<1, 1024, 0, stream>>>(part, out);
}